// Round 1
// baseline (1936.816 us; speedup 1.0000x reference)
//
#include <hip/hip_runtime.h>
#include <hip/hip_bf16.h>
#include <math.h>

typedef unsigned short u16;
typedef __attribute__((ext_vector_type(8))) short short8;
typedef __attribute__((ext_vector_type(4))) float floatx4;

#define B_N 4096
#define P_N 16
#define D_N 512
#define F_N 2048
#define E_N 8
#define TS 4
#define M_ROWS (TS*P_N)      // 64 rows (4 samples x 16 patches)
#define FC 32
#define NCH (F_N/FC)         // 64
#define NPID 64
#define WELEM ((size_t)D_N*F_N)   // 1048576 elems / expert / weight
#define GRID 1072            // >= max tiles: sum_p ceil(c_p/4) <= (4096+63*3)/4 = 1072
#define QX (GRID/8)          // 134 tiles per XCD column

// ---- workspace layout (bytes) ----
#define CNT_OFF   0                        // 64 int
#define PREF_OFF  256                      // 64 int (tile prefix)
#define SL_OFF    4096                     // 64*4096 int
#define GL_OFF    (SL_OFF + NPID*B_N*4)    // 64*4096 float2
#define W1F_OFF   (GL_OFF + NPID*B_N*8)    // 16 MiB frag-linear W1 (bf16)
#define W2F_OFF   (W1F_OFF + 16777216)     // 16 MiB frag-linear W2 (bf16)

__device__ __forceinline__ void gld16(const void* g, void* l) {
  __builtin_amdgcn_global_load_lds(
      (__attribute__((address_space(1))) void*)g,
      (__attribute__((address_space(3))) void*)l, 16, 0, 0);
}

__device__ __forceinline__ short bfq(float x) {
  union { __hip_bfloat16 h; short s; } c; c.h = __float2bfloat16(x); return c.s;
}

// raw barrier that drains LDS ops but NOT the global_load_lds vmcnt queue
__device__ __forceinline__ void bar_lgkm() {
  asm volatile("s_waitcnt lgkmcnt(0)" ::: "memory");
  __builtin_amdgcn_s_barrier();
  asm volatile("" ::: "memory");
}

// ---------------- router: noisy top-2 + pair bucketing (fp32 in) ----------------
__global__ __launch_bounds__(256) void router_kernel(
    const float* __restrict__ aff, const float* __restrict__ noi,
    int* __restrict__ cnt, int* __restrict__ slist, float2* __restrict__ glist)
{
  int b = blockIdx.x*256 + threadIdx.x;
  if (b >= B_N) return;
  float v0 = -INFINITY, v1 = -INFINITY; int i0 = -1, i1 = -1;
  #pragma unroll
  for (int e = 0; e < E_N; ++e) {
    float a = aff[b*E_N + e];
    float n = noi[b*E_N + e];
    float sp = fmaxf(a, 0.f) + log1pf(expf(-fabsf(a)));   // softplus
    float x = a + n * sp;
    if (x > v0) { v1 = v0; i1 = i0; v0 = x; i0 = e; }
    else if (x > v1) { v1 = x; i1 = e; }
  }
  float g0 = 1.f / (1.f + expf(v1 - v0));   // softmax over the two kept logits
  float g1 = 1.f - g0;
  int emin = min(i0, i1), emax = max(i0, i1);
  float glo = (i0 == emin) ? g0 : g1;
  float ghi = (i0 == emin) ? g1 : g0;
  int pid = emin*E_N + emax;
  int pos = atomicAdd(&cnt[pid], 1);
  slist[pid*B_N + pos] = b;
  glist[pid*B_N + pos] = make_float2(glo, ghi);
}

// ---------------- plan: exclusive prefix of per-pair tile counts ----------------
__global__ void plan_kernel(const int* __restrict__ cnt, int* __restrict__ prefix) {
  int lane = threadIdx.x;            // launched with 64 threads (1 wave)
  int nt = (cnt[lane] + TS - 1) / TS;
  int x = nt;
  #pragma unroll
  for (int off = 1; off < 64; off <<= 1) {
    int y = __shfl_up(x, off);
    if (lane >= off) x += y;
  }
  prefix[lane] = x - nt;             // exclusive scan
}

// ---------------- weight prep: fp32 -> bf16 frag-linear order ----------------
// W1 [E][D][F] fp32 -> per (e,fc): [nt(2)][ks(16)][lane(64)][j(8)] bf16
//   f = fc*32 + nt*16 + (lane&15); d = ks*32 + (lane>>4)*8 + j  (B operand: k=d, n=f)
__global__ __launch_bounds__(256) void prep_w1(const float* __restrict__ W1, u16* __restrict__ W1f) {
  int g = blockIdx.x*256 + threadIdx.x;       // 2^20 granules
  int lane = g & 63;
  int ks = (g >> 6) & 15;
  int nt = (g >> 10) & 1;
  int fc = (g >> 11) & 63;
  int e  = (g >> 17) & 7;
  int f  = fc*32 + nt*16 + (lane & 15);
  int d0 = ks*32 + ((lane >> 4) << 3);
  const float* src = W1 + (size_t)e*WELEM + f;
  short8 v;
  #pragma unroll
  for (int j = 0; j < 8; ++j) v[j] = bfq(src[(size_t)(d0 + j)*F_N]);
  ((short8*)W1f)[g] = v;
}
// W2 [E][F][D] fp32 -> per (e,fc): [nt(32)][lane(64)][j(8)] bf16
//   d = nt*16 + (lane&15); f = fc*32 + (lane>>4)*8 + j  (B operand: k=f, n=d)
__global__ __launch_bounds__(256) void prep_w2(const float* __restrict__ W2, u16* __restrict__ W2f) {
  int g = blockIdx.x*256 + threadIdx.x;
  int lane = g & 63;
  int nt = (g >> 6) & 31;
  int fc = (g >> 11) & 63;
  int e  = (g >> 17) & 7;
  int d  = nt*16 + (lane & 15);
  int f0 = fc*32 + ((lane >> 4) << 3);
  const float* src = W2 + (size_t)e*WELEM + d;
  short8 v;
  #pragma unroll
  for (int j = 0; j < 8; ++j) v[j] = bfq(src[(size_t)(f0 + j)*D_N]);
  ((short8*)W2f)[g] = v;
}

// ---------------- fused MoE MLP: per block = 4 samples x both experts ----------------
__global__ __launch_bounds__(512, 2) void moe_main(
    const float* __restrict__ X,
    const u16* __restrict__ W1f, const u16* __restrict__ W2f,
    const float* __restrict__ b1, const float* __restrict__ b2,
    const int* __restrict__ cnt, const int* __restrict__ prefix,
    const int* __restrict__ slist, const float2* __restrict__ glist,
    float* __restrict__ out)
{
  __shared__ u16 X_lds[M_ROWS][520];   // 66560 B (+8 pad keeps A-frag reads low-conflict)
  __shared__ u16 Wbuf[2][FC*D_N];      // 2 x 32 KB double buffer (buf0=W1, buf1=W2)
  __shared__ u16 h_lds[M_ROWS][40];    // 5120 B gated gelu(h) chunk

  const int tid = threadIdx.x;
  const int lane = tid & 63;
  const int wave = tid >> 6;           // 0..7

  // XCD-chunked virtual tile id: consecutive tiles of one pair land on one XCD's L2
  const int t = (blockIdx.x & 7)*QX + (blockIdx.x >> 3);
  int pf = prefix[lane];
  unsigned long long bal = __ballot(pf <= t);
  int pid = __popcll(bal) - 1;
  int tile = t - __shfl(pf, pid);
  int c = cnt[pid];
  if (tile >= (c + TS - 1)/TS) return;
  const int base = tile*TS;
  const int nsamp = min(TS, c - base);

  const int e_lo = pid >> 3, e_hi = pid & 7;
  const int sb = pid*B_N + base;
  int s0v = slist[sb];       float2 g0v = glist[sb];
  int s1v = s0v, s2v = s0v, s3v = s0v;
  float2 zz = make_float2(0.f, 0.f);
  float2 g1v = zz, g2v = zz, g3v = zz;
  if (nsamp > 1) { s1v = slist[sb+1]; g1v = glist[sb+1]; }
  if (nsamp > 2) { s2v = slist[sb+2]; g2v = glist[sb+2]; }
  if (nsamp > 3) { s3v = slist[sb+3]; g3v = glist[sb+3]; }

  const u16* w1lo = W1f + (size_t)e_lo*WELEM;
  const u16* w1hi = W1f + (size_t)e_hi*WELEM;
  const u16* w2lo = W2f + (size_t)e_lo*WELEM;
  const u16* w2hi = W2f + (size_t)e_hi*WELEM;

  // prologue: issue W1[cc=0] -> buf0 (4 gld16/wave outstanding; lands under X staging)
  {
    #pragma unroll
    for (int i = 0; i < 4; ++i) {
      int gidx = wave*256 + i*64;
      gld16(w1lo + (size_t)(gidx + lane)*8, &Wbuf[0][(size_t)gidx*8]);
    }
  }

  // stage X: 64 rows x 512 fp32 -> bf16 LDS (compile-time sample index per k)
  {
    const int gc = tid & 63;
    #pragma unroll
    for (int k = 0; k < 8; ++k) {
      int r = wave + k*8;              // r>>4 == k>>1 (compile-time)
      int smp = (k>>1)==0 ? s0v : (k>>1)==1 ? s1v : (k>>1)==2 ? s2v : s3v;
      const float* src = X + (size_t)(smp*P_N + (r & 15))*D_N + gc*8;
      float4 f0 = *(const float4*)(src);
      float4 f1 = *(const float4*)(src + 4);
      short8 v;
      v[0]=bfq(f0.x); v[1]=bfq(f0.y); v[2]=bfq(f0.z); v[3]=bfq(f0.w);
      v[4]=bfq(f1.x); v[5]=bfq(f1.y); v[6]=bfq(f1.z); v[7]=bfq(f1.w);
      *(short8*)&X_lds[r][gc*8] = v;
    }
  }

  floatx4 Yacc[2][8];
  #pragma unroll
  for (int a = 0; a < 2; ++a)
    #pragma unroll
    for (int q = 0; q < 8; ++q) Yacc[a][q] = (floatx4){0.f,0.f,0.f,0.f};

  const int rA = lane & 15;
  const int cA = (lane >> 4) * 8;
  const int mt1 = wave & 3, nt1 = wave >> 2;   // GEMM1: 4 m-tiles x 2 n-tiles
  const int mh  = wave & 1, dq  = wave >> 1;   // GEMM2: 2 m-halves x 4 d-quads
  const float2 gmt = (mt1==0) ? g0v : (mt1==1) ? g1v : (mt1==2) ? g2v : g3v;

  for (int cc = 0; cc < 2*NCH; ++cc) {
    const int xp = cc >> 6;
    const int fc = cc & 63;
    const int e  = xp ? e_hi : e_lo;

    { // stage W2[cc] -> buf1 (prev GEMM2 finished reading buf1 before last barrier)
      const u16* gsrc = (xp ? w2hi : w2lo) + (size_t)fc*FC*D_N;
      #pragma unroll
      for (int i = 0; i < 4; ++i) {
        int gidx = wave*256 + i*64;
        gld16(gsrc + (size_t)(gidx + lane)*8, &Wbuf[1][(size_t)gidx*8]);
      }
    }
    asm volatile("s_waitcnt vmcnt(4)" ::: "memory");   // W1[cc] landed (W2[cc] still in flight)
    bar_lgkm();                                        // all waves' W1 visible (+X on cc==0)

    // GEMM1: h[64x32] over K=512
    floatx4 acc1 = (floatx4){0.f,0.f,0.f,0.f};
    #pragma unroll
    for (int ks = 0; ks < 16; ++ks) {
      short8 a  = *(const short8*)&X_lds[mt1*16 + rA][ks*32 + cA];
      short8 bb = *(const short8*)&Wbuf[0][((nt1*16 + ks)*64 + lane)*8];
      acc1 = __builtin_amdgcn_mfma_f32_16x16x32_bf16(a, bb, acc1, 0, 0, 0);
    }
    { // bias + tanh-GELU + gate fold, h -> LDS
      float b1v = b1[e*F_N + fc*FC + nt1*16 + rA];
      float gate = xp ? gmt.y : gmt.x;
      #pragma unroll
      for (int i = 0; i < 4; ++i) {
        float v = acc1[i] + b1v;
        float u = 0.7978845608028654f * (v + 0.044715f*v*v*v);
        float hq = 0.5f * v * (1.f + tanhf(u)) * gate;
        h_lds[mt1*16 + (lane>>4)*4 + i][nt1*16 + rA] = (u16)bfq(hq);
      }
    }
    bar_lgkm();                                        // h visible; buf0 reads done

    { // stage W1[cc+1] -> buf0 (lands under GEMM2; dummy re-stage on last iter)
      int nc = (cc + 1 < 2*NCH) ? cc + 1 : cc;
      const u16* wn = ((nc >> 6) ? w1hi : w1lo) + (size_t)(nc & 63)*FC*D_N;
      #pragma unroll
      for (int i = 0; i < 4; ++i) {
        int gidx = wave*256 + i*64;
        gld16(wn + (size_t)(gidx + lane)*8, &Wbuf[0][(size_t)gidx*8]);
      }
    }
    asm volatile("s_waitcnt vmcnt(4)" ::: "memory");   // W2[cc] landed (W1[cc+1] in flight)
    bar_lgkm();

    // GEMM2: Y[64x512] += h[64x32] @ W2chunk[32x512]; wave owns rows mh*32.., d in dq*128..
    short8 a0 = *(const short8*)&h_lds[mh*32 + rA][cA];
    short8 a1 = *(const short8*)&h_lds[mh*32 + 16 + rA][cA];
    #pragma unroll
    for (int n2 = 0; n2 < 8; ++n2) {
      short8 bb = *(const short8*)&Wbuf[1][((dq*8 + n2)*64 + lane)*8];
      Yacc[0][n2] = __builtin_amdgcn_mfma_f32_16x16x32_bf16(a0, bb, Yacc[0][n2], 0, 0, 0);
      Yacc[1][n2] = __builtin_amdgcn_mfma_f32_16x16x32_bf16(a1, bb, Yacc[1][n2], 0, 0, 0);
    }
    bar_lgkm();                                        // buf1 + h reads done -> next iter may overwrite
  }
  asm volatile("s_waitcnt vmcnt(0)" ::: "memory");     // drain dummy stage before epilogue/end

  // epilogue: out[b,p,d] = Y + gate-weighted b2 (C-layout: col=lane&15, row=quad*4+i)
  const int   sA = mh ? s2v : s0v;  const float2 gA = mh ? g2v : g0v;
  const int   sB = mh ? s3v : s1v;  const float2 gB = mh ? g3v : g1v;
  #pragma unroll
  for (int mt = 0; mt < 2; ++mt) {
    int si = mh*2 + mt;
    if (si >= nsamp) continue;
    int smp = mt ? sB : sA;
    float2 gv = mt ? gB : gA;
    #pragma unroll
    for (int n2 = 0; n2 < 8; ++n2) {
      int dcol = dq*128 + n2*16 + rA;
      float b2v = gv.x * b2[e_lo*D_N + dcol]
                + gv.y * b2[e_hi*D_N + dcol];
      #pragma unroll
      for (int i = 0; i < 4; ++i) {
        int p = (lane >> 4)*4 + i;
        out[(size_t)(smp*P_N + p)*D_N + dcol] = Yacc[mt][n2][i] + b2v;
      }
    }
  }
}

extern "C" void kernel_launch(void* const* d_in, const int* in_sizes, int n_in,
                              void* d_out, int out_size, void* d_ws, size_t ws_size,
                              hipStream_t stream) {
  const float* X   = (const float*)d_in[0];
  // d_in[1] patch_embedding: only defines output shape; values unused
  const float* aff = (const float*)d_in[2];
  const float* noi = (const float*)d_in[3];
  const float* W1  = (const float*)d_in[4];
  const float* b1  = (const float*)d_in[5];
  const float* W2  = (const float*)d_in[6];
  const float* b2  = (const float*)d_in[7];

  char* ws   = (char*)d_ws;
  int* cnt   = (int*)(ws + CNT_OFF);
  int* pref  = (int*)(ws + PREF_OFF);
  int* slist = (int*)(ws + SL_OFF);
  float2* glist = (float2*)(ws + GL_OFF);
  u16* W1f   = (u16*)(ws + W1F_OFF);
  u16* W2f   = (u16*)(ws + W2F_OFF);

  hipMemsetAsync(cnt, 0, NPID*sizeof(int), stream);
  hipLaunchKernelGGL(router_kernel, dim3(B_N/256), dim3(256), 0, stream, aff, noi, cnt, slist, glist);
  hipLaunchKernelGGL(plan_kernel, dim3(1), dim3(64), 0, stream, cnt, pref);
  hipLaunchKernelGGL(prep_w1, dim3(4096), dim3(256), 0, stream, W1, (u16*)W1f);
  hipLaunchKernelGGL(prep_w2, dim3(4096), dim3(256), 0, stream, W2, (u16*)W2f);
  hipLaunchKernelGGL(moe_main, dim3(GRID), dim3(512), 0, stream,
                     X, W1f, W2f, b1, b2, cnt, pref, slist, glist, (float*)d_out);
}

// Round 2
// 1831.500 us; speedup vs baseline: 1.0575x; 1.0575x over previous
//
#include <hip/hip_runtime.h>
#include <hip/hip_bf16.h>
#include <math.h>

typedef unsigned short u16;
typedef __attribute__((ext_vector_type(8))) short short8;
typedef __attribute__((ext_vector_type(4))) float floatx4;

#define B_N 4096
#define P_N 16
#define D_N 512
#define F_N 2048
#define E_N 8
#define TS 4
#define M_ROWS (TS*P_N)      // 64 rows (4 samples x 16 patches)
#define FC 32
#define NCH (F_N/FC)         // 64
#define NPID 64
#define WELEM ((size_t)D_N*F_N)   // 1048576 elems / expert / weight
#define GRID 1072            // >= max tiles: sum_p ceil(c_p/4) <= (4096+63*3)/4 = 1072
#define QX (GRID/8)          // 134 tiles per XCD column

// ---- workspace layout (bytes) ----
#define CNT_OFF   0                        // 64 int
#define PREF_OFF  256                      // 64 int (tile prefix)
#define SL_OFF    4096                     // 64*4096 int
#define GL_OFF    (SL_OFF + NPID*B_N*4)    // 64*4096 float2
#define W1F_OFF   (GL_OFF + NPID*B_N*8)    // 16 MiB frag-linear W1 (bf16)
#define W2F_OFF   (W1F_OFF + 16777216)     // 16 MiB frag-linear W2 (bf16)

__device__ __forceinline__ void gld16(const void* g, void* l) {
  __builtin_amdgcn_global_load_lds(
      (__attribute__((address_space(1))) void*)g,
      (__attribute__((address_space(3))) void*)l, 16, 0, 0);
}

__device__ __forceinline__ short bfq(float x) {
  union { __hip_bfloat16 h; short s; } c; c.h = __float2bfloat16(x); return c.s;
}

// raw barrier that drains LDS ops but NOT the global_load_lds vmcnt queue
__device__ __forceinline__ void bar_lgkm() {
  asm volatile("s_waitcnt lgkmcnt(0)" ::: "memory");
  __builtin_amdgcn_s_barrier();
  asm volatile("" ::: "memory");
}

// ---------------- router: noisy top-2 + pair bucketing (fp32 in) ----------------
__global__ __launch_bounds__(256) void router_kernel(
    const float* __restrict__ aff, const float* __restrict__ noi,
    int* __restrict__ cnt, int* __restrict__ slist, float2* __restrict__ glist)
{
  int b = blockIdx.x*256 + threadIdx.x;
  if (b >= B_N) return;
  float v0 = -INFINITY, v1 = -INFINITY; int i0 = -1, i1 = -1;
  #pragma unroll
  for (int e = 0; e < E_N; ++e) {
    float a = aff[b*E_N + e];
    float n = noi[b*E_N + e];
    float sp = fmaxf(a, 0.f) + log1pf(expf(-fabsf(a)));   // softplus
    float x = a + n * sp;
    if (x > v0) { v1 = v0; i1 = i0; v0 = x; i0 = e; }
    else if (x > v1) { v1 = x; i1 = e; }
  }
  float g0 = 1.f / (1.f + expf(v1 - v0));   // softmax over the two kept logits
  float g1 = 1.f - g0;
  int emin = min(i0, i1), emax = max(i0, i1);
  float glo = (i0 == emin) ? g0 : g1;
  float ghi = (i0 == emin) ? g1 : g0;
  int pid = emin*E_N + emax;
  int pos = atomicAdd(&cnt[pid], 1);
  slist[pid*B_N + pos] = b;
  glist[pid*B_N + pos] = make_float2(glo, ghi);
}

// ---------------- plan: exclusive prefix of per-pair tile counts ----------------
__global__ void plan_kernel(const int* __restrict__ cnt, int* __restrict__ prefix) {
  int lane = threadIdx.x;            // launched with 64 threads (1 wave)
  int nt = (cnt[lane] + TS - 1) / TS;
  int x = nt;
  #pragma unroll
  for (int off = 1; off < 64; off <<= 1) {
    int y = __shfl_up(x, off);
    if (lane >= off) x += y;
  }
  prefix[lane] = x - nt;             // exclusive scan
}

// ---------------- weight prep: fp32 -> bf16 frag-linear order ----------------
// W1 [E][D][F] fp32 -> per (e,fc): [nt(2)][ks(16)][lane(64)][j(8)] bf16
//   f = fc*32 + nt*16 + (lane&15); d = ks*32 + (lane>>4)*8 + j  (B operand: k=d, n=f)
__global__ __launch_bounds__(256) void prep_w1(const float* __restrict__ W1, u16* __restrict__ W1f) {
  int g = blockIdx.x*256 + threadIdx.x;       // 2^20 granules
  int lane = g & 63;
  int ks = (g >> 6) & 15;
  int nt = (g >> 10) & 1;
  int fc = (g >> 11) & 63;
  int e  = (g >> 17) & 7;
  int f  = fc*32 + nt*16 + (lane & 15);
  int d0 = ks*32 + ((lane >> 4) << 3);
  const float* src = W1 + (size_t)e*WELEM + f;
  short8 v;
  #pragma unroll
  for (int j = 0; j < 8; ++j) v[j] = bfq(src[(size_t)(d0 + j)*F_N]);
  ((short8*)W1f)[g] = v;
}
// W2 [E][F][D] fp32 -> per (e,fc): [nt(32)][lane(64)][j(8)] bf16
//   d = nt*16 + (lane&15); f = fc*32 + (lane>>4)*8 + j  (B operand: k=f, n=d)
__global__ __launch_bounds__(256) void prep_w2(const float* __restrict__ W2, u16* __restrict__ W2f) {
  int g = blockIdx.x*256 + threadIdx.x;
  int lane = g & 63;
  int nt = (g >> 6) & 31;
  int fc = (g >> 11) & 63;
  int e  = (g >> 17) & 7;
  int d  = nt*16 + (lane & 15);
  int f0 = fc*32 + ((lane >> 4) << 3);
  const float* src = W2 + (size_t)e*WELEM + d;
  short8 v;
  #pragma unroll
  for (int j = 0; j < 8; ++j) v[j] = bfq(src[(size_t)(f0 + j)*D_N]);
  ((short8*)W2f)[g] = v;
}

// ---------------- fused MoE MLP: per block = 4 samples x both experts ----------------
__global__ __launch_bounds__(512, 2) void moe_main(
    const float* __restrict__ X,
    const u16* __restrict__ W1f, const u16* __restrict__ W2f,
    const float* __restrict__ b1, const float* __restrict__ b2,
    const int* __restrict__ cnt, const int* __restrict__ prefix,
    const int* __restrict__ slist, const float2* __restrict__ glist,
    float* __restrict__ out)
{
  __shared__ u16 X_lds[M_ROWS][520];   // 66560 B; only used once (A-frag hoist)
  __shared__ u16 Wbuf[2][FC*D_N];      // 2 x 32 KB double buffer (buf0=W1, buf1=W2)
  __shared__ u16 hfl[4*512];           // 4 KB, frag-linear h: [blk(4)][lane(64)][j(8)]

  const int tid = threadIdx.x;
  const int lane = tid & 63;
  const int wave = tid >> 6;           // 0..7

  // XCD-chunked virtual tile id: consecutive tiles of one pair land on one XCD's L2
  const int t = (blockIdx.x & 7)*QX + (blockIdx.x >> 3);
  int pf = prefix[lane];
  unsigned long long bal = __ballot(pf <= t);
  int pid = __popcll(bal) - 1;
  int tile = t - __shfl(pf, pid);
  int c = cnt[pid];
  if (tile >= (c + TS - 1)/TS) return;
  const int base = tile*TS;
  const int nsamp = min(TS, c - base);

  const int e_lo = pid >> 3, e_hi = pid & 7;
  const int sb = pid*B_N + base;
  int s0v = slist[sb];       float2 g0v = glist[sb];
  int s1v = s0v, s2v = s0v, s3v = s0v;
  float2 zz = make_float2(0.f, 0.f);
  float2 g1v = zz, g2v = zz, g3v = zz;
  if (nsamp > 1) { s1v = slist[sb+1]; g1v = glist[sb+1]; }
  if (nsamp > 2) { s2v = slist[sb+2]; g2v = glist[sb+2]; }
  if (nsamp > 3) { s3v = slist[sb+3]; g3v = glist[sb+3]; }

  const u16* w1lo = W1f + (size_t)e_lo*WELEM;
  const u16* w1hi = W1f + (size_t)e_hi*WELEM;
  const u16* w2lo = W2f + (size_t)e_lo*WELEM;
  const u16* w2hi = W2f + (size_t)e_hi*WELEM;

  // prologue: issue W1[cc=0] -> buf0 (4 gld16/wave outstanding; lands under X staging)
  {
    #pragma unroll
    for (int i = 0; i < 4; ++i) {
      int gidx = wave*256 + i*64;
      gld16(w1lo + (size_t)(gidx + lane)*8, &Wbuf[0][(size_t)gidx*8]);
    }
  }

  // stage X: 64 rows x 512 fp32 -> bf16 LDS (compile-time sample index per k)
  {
    const int gc = tid & 63;
    #pragma unroll
    for (int k = 0; k < 8; ++k) {
      int r = wave + k*8;              // r>>4 == k>>1 (compile-time)
      int smp = (k>>1)==0 ? s0v : (k>>1)==1 ? s1v : (k>>1)==2 ? s2v : s3v;
      const float* src = X + (size_t)(smp*P_N + (r & 15))*D_N + gc*8;
      float4 f0 = *(const float4*)(src);
      float4 f1 = *(const float4*)(src + 4);
      short8 v;
      v[0]=bfq(f0.x); v[1]=bfq(f0.y); v[2]=bfq(f0.z); v[3]=bfq(f0.w);
      v[4]=bfq(f1.x); v[5]=bfq(f1.y); v[6]=bfq(f1.z); v[7]=bfq(f1.w);
      *(short8*)&X_lds[r][gc*8] = v;
    }
  }

  const int rA = lane & 15;
  const int cA = (lane >> 4) * 8;
  const int mt1 = wave & 3, nt1 = wave >> 2;   // GEMM1: 4 m-tiles x 2 n-tiles
  const int mh  = wave & 1, dq  = wave >> 1;   // GEMM2: 2 m-halves x 4 d-quads
  const float2 gmt = (mt1==0) ? g0v : (mt1==1) ? g1v : (mt1==2) ? g2v : g3v;

  bar_lgkm();                                  // X visible (W1[0] still in flight: vmcnt)

  // A-frag hoist: this wave's 16 GEMM1 rows x K=512 -> 16 short8 = 64 VGPR (one-time)
  short8 areg[16];
  #pragma unroll
  for (int ks = 0; ks < 16; ++ks)
    areg[ks] = *(const short8*)&X_lds[mt1*16 + rA][ks*32 + cA];

  floatx4 Yacc[2][8];
  #pragma unroll
  for (int a = 0; a < 2; ++a)
    #pragma unroll
    for (int q = 0; q < 8; ++q) Yacc[a][q] = (floatx4){0.f,0.f,0.f,0.f};

  for (int cc = 0; cc < 2*NCH; ++cc) {
    const int xp = cc >> 6;
    const int fc = cc & 63;
    const int e  = xp ? e_hi : e_lo;

    { // stage W2[cc] -> buf1 (prev GEMM2 finished reading buf1 before last barrier)
      const u16* gsrc = (xp ? w2hi : w2lo) + (size_t)fc*FC*D_N;
      #pragma unroll
      for (int i = 0; i < 4; ++i) {
        int gidx = wave*256 + i*64;
        gld16(gsrc + (size_t)(gidx + lane)*8, &Wbuf[1][(size_t)gidx*8]);
      }
    }
    asm volatile("s_waitcnt vmcnt(4)" ::: "memory");   // W1[cc] landed (W2[cc] still in flight)
    bar_lgkm();                                        // all waves' W1 visible

    // GEMM1: h[64x32] over K=512; A from registers, B lane-linear (conflict-free)
    floatx4 acc1 = (floatx4){0.f,0.f,0.f,0.f};
    __builtin_amdgcn_s_setprio(1);
    #pragma unroll
    for (int ks = 0; ks < 16; ++ks) {
      short8 bb = *(const short8*)&Wbuf[0][((nt1*16 + ks)*64 + lane)*8];
      acc1 = __builtin_amdgcn_mfma_f32_16x16x32_bf16(areg[ks], bb, acc1, 0, 0, 0);
    }
    __builtin_amdgcn_s_setprio(0);
    { // bias + tanh-GELU + gate fold -> frag-linear h
      float b1v = b1[e*F_N + fc*FC + nt1*16 + rA];
      float gate = xp ? gmt.y : gmt.x;
      int wbase = mt1*512 + (nt1*2 + (rA >> 3))*128 + (rA & 7) + (lane >> 4)*32;
      #pragma unroll
      for (int i = 0; i < 4; ++i) {
        float v = acc1[i] + b1v;
        float u = 0.7978845608028654f * (v + 0.044715f*v*v*v);
        float hq = 0.5f * v * (1.f + tanhf(u)) * gate;
        // hr = mt1*16 + (lane>>4)*4 + i, f = nt1*16 + rA
        hfl[wbase + i*8] = (u16)bfq(hq);
      }
    }
    bar_lgkm();                                        // h visible; buf0 reads done

    { // stage W1[cc+1] -> buf0 (lands under GEMM2; dummy re-stage on last iter)
      int nc = (cc + 1 < 2*NCH) ? cc + 1 : cc;
      const u16* wn = ((nc >> 6) ? w1hi : w1lo) + (size_t)(nc & 63)*FC*D_N;
      #pragma unroll
      for (int i = 0; i < 4; ++i) {
        int gidx = wave*256 + i*64;
        gld16(wn + (size_t)(gidx + lane)*8, &Wbuf[0][(size_t)gidx*8]);
      }
    }
    asm volatile("s_waitcnt vmcnt(4)" ::: "memory");   // W2[cc] landed (W1[cc+1] in flight)
    bar_lgkm();

    // GEMM2: Y[64x512] += h[64x32] @ W2chunk[32x512]; wave owns rows mh*32.., d in dq*128..
    short8 a0 = *(const short8*)&hfl[(2*mh)*512 + lane*8];       // conflict-free
    short8 a1 = *(const short8*)&hfl[(2*mh + 1)*512 + lane*8];
    __builtin_amdgcn_s_setprio(1);
    #pragma unroll
    for (int n2 = 0; n2 < 8; ++n2) {
      short8 bb = *(const short8*)&Wbuf[1][((dq*8 + n2)*64 + lane)*8];
      Yacc[0][n2] = __builtin_amdgcn_mfma_f32_16x16x32_bf16(a0, bb, Yacc[0][n2], 0, 0, 0);
      Yacc[1][n2] = __builtin_amdgcn_mfma_f32_16x16x32_bf16(a1, bb, Yacc[1][n2], 0, 0, 0);
    }
    __builtin_amdgcn_s_setprio(0);
    bar_lgkm();                                        // buf1 + h reads done -> next iter may overwrite
  }
  asm volatile("s_waitcnt vmcnt(0)" ::: "memory");     // drain dummy stage before epilogue/end

  // epilogue: out[b,p,d] = Y + gate-weighted b2 (C-layout: col=lane&15, row=quad*4+i)
  const int   sA = mh ? s2v : s0v;  const float2 gA = mh ? g2v : g0v;
  const int   sB = mh ? s3v : s1v;  const float2 gB = mh ? g3v : g1v;
  #pragma unroll
  for (int mt = 0; mt < 2; ++mt) {
    int si = mh*2 + mt;
    if (si >= nsamp) continue;
    int smp = mt ? sB : sA;
    float2 gv = mt ? gB : gA;
    #pragma unroll
    for (int n2 = 0; n2 < 8; ++n2) {
      int dcol = dq*128 + n2*16 + rA;
      float b2v = gv.x * b2[e_lo*D_N + dcol]
                + gv.y * b2[e_hi*D_N + dcol];
      #pragma unroll
      for (int i = 0; i < 4; ++i) {
        int p = (lane >> 4)*4 + i;
        out[(size_t)(smp*P_N + p)*D_N + dcol] = Yacc[mt][n2][i] + b2v;
      }
    }
  }
}

extern "C" void kernel_launch(void* const* d_in, const int* in_sizes, int n_in,
                              void* d_out, int out_size, void* d_ws, size_t ws_size,
                              hipStream_t stream) {
  const float* X   = (const float*)d_in[0];
  // d_in[1] patch_embedding: only defines output shape; values unused
  const float* aff = (const float*)d_in[2];
  const float* noi = (const float*)d_in[3];
  const float* W1  = (const float*)d_in[4];
  const float* b1  = (const float*)d_in[5];
  const float* W2  = (const float*)d_in[6];
  const float* b2  = (const float*)d_in[7];

  char* ws   = (char*)d_ws;
  int* cnt   = (int*)(ws + CNT_OFF);
  int* pref  = (int*)(ws + PREF_OFF);
  int* slist = (int*)(ws + SL_OFF);
  float2* glist = (float2*)(ws + GL_OFF);
  u16* W1f   = (u16*)(ws + W1F_OFF);
  u16* W2f   = (u16*)(ws + W2F_OFF);

  hipMemsetAsync(cnt, 0, NPID*sizeof(int), stream);
  hipLaunchKernelGGL(router_kernel, dim3(B_N/256), dim3(256), 0, stream, aff, noi, cnt, slist, glist);
  hipLaunchKernelGGL(plan_kernel, dim3(1), dim3(64), 0, stream, cnt, pref);
  hipLaunchKernelGGL(prep_w1, dim3(4096), dim3(256), 0, stream, W1, (u16*)W1f);
  hipLaunchKernelGGL(prep_w2, dim3(4096), dim3(256), 0, stream, W2, (u16*)W2f);
  hipLaunchKernelGGL(moe_main, dim3(GRID), dim3(512), 0, stream,
                     X, W1f, W2f, b1, b2, cnt, pref, slist, glist, (float*)d_out);
}

// Round 3
// 1430.228 us; speedup vs baseline: 1.3542x; 1.2806x over previous
//
#include <hip/hip_runtime.h>
#include <hip/hip_bf16.h>
#include <math.h>

typedef unsigned short u16;
typedef __attribute__((ext_vector_type(8))) short short8;
typedef __attribute__((ext_vector_type(4))) float floatx4;

#define B_N 4096
#define P_N 16
#define D_N 512
#define F_N 2048
#define E_N 8
#define TS 4
#define FC 32
#define NCH (F_N/FC)         // 64
#define NPID 64
#define WELEM ((size_t)D_N*F_N)   // 1048576 elems / expert / weight
#define GRID 1072            // >= max tiles: sum_p ceil(c_p/4) <= (4096+63*3)/4 = 1072
#define QX (GRID/8)          // 134 tiles per XCD column

// ---- workspace layout (bytes) ----
#define CNT_OFF   0                        // 64 int
#define PREF_OFF  256                      // 64 int (tile prefix)
#define SL_OFF    4096                     // 64*4096 int
#define GL_OFF    (SL_OFF + NPID*B_N*4)    // 64*4096 float2
#define W1F_OFF   (GL_OFF + NPID*B_N*8)    // 16 MiB frag-linear W1 (bf16)
#define W2F_OFF   (W1F_OFF + 16777216)     // 16 MiB frag-linear W2 (bf16)

__device__ __forceinline__ void gld16(const void* g, void* l) {
  __builtin_amdgcn_global_load_lds(
      (__attribute__((address_space(1))) void*)g,
      (__attribute__((address_space(3))) void*)l, 16, 0, 0);
}

__device__ __forceinline__ short bfq(float x) {
  union { __hip_bfloat16 h; short s; } c; c.h = __float2bfloat16(x); return c.s;
}

// raw barrier that drains LDS ops but NOT the global_load_lds vmcnt queue
__device__ __forceinline__ void bar_lgkm() {
  asm volatile("s_waitcnt lgkmcnt(0)" ::: "memory");
  __builtin_amdgcn_s_barrier();
  asm volatile("" ::: "memory");
}

// ---------------- router: noisy top-2 + pair bucketing (fp32 in) ----------------
__global__ __launch_bounds__(256) void router_kernel(
    const float* __restrict__ aff, const float* __restrict__ noi,
    int* __restrict__ cnt, int* __restrict__ slist, float2* __restrict__ glist)
{
  int b = blockIdx.x*256 + threadIdx.x;
  if (b >= B_N) return;
  float v0 = -INFINITY, v1 = -INFINITY; int i0 = -1, i1 = -1;
  #pragma unroll
  for (int e = 0; e < E_N; ++e) {
    float a = aff[b*E_N + e];
    float n = noi[b*E_N + e];
    float sp = fmaxf(a, 0.f) + log1pf(expf(-fabsf(a)));   // softplus
    float x = a + n * sp;
    if (x > v0) { v1 = v0; i1 = i0; v0 = x; i0 = e; }
    else if (x > v1) { v1 = x; i1 = e; }
  }
  float g0 = 1.f / (1.f + expf(v1 - v0));   // softmax over the two kept logits
  float g1 = 1.f - g0;
  int emin = min(i0, i1), emax = max(i0, i1);
  float glo = (i0 == emin) ? g0 : g1;
  float ghi = (i0 == emin) ? g1 : g0;
  int pid = emin*E_N + emax;
  int pos = atomicAdd(&cnt[pid], 1);
  slist[pid*B_N + pos] = b;
  glist[pid*B_N + pos] = make_float2(glo, ghi);
}

// ---------------- plan: exclusive prefix of per-pair tile counts ----------------
__global__ void plan_kernel(const int* __restrict__ cnt, int* __restrict__ prefix) {
  int lane = threadIdx.x;            // launched with 64 threads (1 wave)
  int nt = (cnt[lane] + TS - 1) / TS;
  int x = nt;
  #pragma unroll
  for (int off = 1; off < 64; off <<= 1) {
    int y = __shfl_up(x, off);
    if (lane >= off) x += y;
  }
  prefix[lane] = x - nt;             // exclusive scan
}

// ---------------- weight prep: fp32 -> bf16 frag-linear order ----------------
// W1 [E][D][F] fp32 -> per (e,fc): [nt(2)][ks(16)][lane(64)][j(8)] bf16
//   f = fc*32 + nt*16 + (lane&15); d = ks*32 + (lane>>4)*8 + j  (B operand: k=d, n=f)
__global__ __launch_bounds__(256) void prep_w1(const float* __restrict__ W1, u16* __restrict__ W1f) {
  int g = blockIdx.x*256 + threadIdx.x;       // 2^20 granules
  int lane = g & 63;
  int ks = (g >> 6) & 15;
  int nt = (g >> 10) & 1;
  int fc = (g >> 11) & 63;
  int e  = (g >> 17) & 7;
  int f  = fc*32 + nt*16 + (lane & 15);
  int d0 = ks*32 + ((lane >> 4) << 3);
  const float* src = W1 + (size_t)e*WELEM + f;
  short8 v;
  #pragma unroll
  for (int j = 0; j < 8; ++j) v[j] = bfq(src[(size_t)(d0 + j)*F_N]);
  ((short8*)W1f)[g] = v;
}
// W2 [E][F][D] fp32 -> per (e,fc): [nt(32)][lane(64)][j(8)] bf16
//   d = nt*16 + (lane&15); f = fc*32 + (lane>>4)*8 + j  (B operand: k=f, n=d)
__global__ __launch_bounds__(256) void prep_w2(const float* __restrict__ W2, u16* __restrict__ W2f) {
  int g = blockIdx.x*256 + threadIdx.x;
  int lane = g & 63;
  int nt = (g >> 6) & 31;
  int fc = (g >> 11) & 63;
  int e  = (g >> 17) & 7;
  int d  = nt*16 + (lane & 15);
  int f0 = fc*32 + ((lane >> 4) << 3);
  const float* src = W2 + (size_t)e*WELEM + d;
  short8 v;
  #pragma unroll
  for (int j = 0; j < 8; ++j) v[j] = bfq(src[(size_t)(f0 + j)*D_N]);
  ((short8*)W2f)[g] = v;
}

// ---------------- fused MoE MLP: 256 threads, 4 waves, 2 blocks/CU ----------------
// wave w: GEMM1 owns sample w (full 32 f-cols); GEMM2 owns samples {w&1, (w&1)+2} x d-half (w>>1)
__global__ __launch_bounds__(256, 2) void moe_main(
    const float* __restrict__ X,
    const u16* __restrict__ W1f, const u16* __restrict__ W2f,
    const float* __restrict__ b1, const float* __restrict__ b2,
    const int* __restrict__ cnt, const int* __restrict__ prefix,
    const int* __restrict__ slist, const float2* __restrict__ glist,
    float* __restrict__ out)
{
  __shared__ u16 Wbuf[2][FC*D_N];      // 2 x 32 KB double buffer (buf0=W1, buf1=W2)
  __shared__ u16 hfl[4*512];           // 4 KB, frag-linear h: [samp(4)][lane(64)][j(8)]

  const int tid = threadIdx.x;
  const int lane = tid & 63;
  const int wave = tid >> 6;           // 0..3

  // XCD-chunked virtual tile id: consecutive tiles of one pair land on one XCD's L2
  const int t = (blockIdx.x & 7)*QX + (blockIdx.x >> 3);
  int pf = prefix[lane];
  unsigned long long bal = __ballot(pf <= t);
  int pid = __popcll(bal) - 1;
  int tile = t - __shfl(pf, pid);
  int c = cnt[pid];
  if (tile >= (c + TS - 1)/TS) return;
  const int base = tile*TS;
  const int nsamp = min(TS, c - base);

  const int e_lo = pid >> 3, e_hi = pid & 7;
  const int sb = pid*B_N + base;
  int s0v = slist[sb];       float2 g0v = glist[sb];
  int s1v = s0v, s2v = s0v, s3v = s0v;
  float2 zz = make_float2(0.f, 0.f);
  float2 g1v = zz, g2v = zz, g3v = zz;
  if (nsamp > 1) { s1v = slist[sb+1]; g1v = glist[sb+1]; }
  if (nsamp > 2) { s2v = slist[sb+2]; g2v = glist[sb+2]; }
  if (nsamp > 3) { s3v = slist[sb+3]; g3v = glist[sb+3]; }

  const u16* w1lo = W1f + (size_t)e_lo*WELEM;
  const u16* w1hi = W1f + (size_t)e_hi*WELEM;
  const u16* w2lo = W2f + (size_t)e_lo*WELEM;
  const u16* w2hi = W2f + (size_t)e_hi*WELEM;

  const int rA = lane & 15;
  const int cA = (lane >> 4) * 8;

  // per-wave GEMM1 sample + gates (uniform per wave)
  const int   smpw = (wave==0) ? s0v : (wave==1) ? s1v : (wave==2) ? s2v : s3v;
  const float2 gw  = (wave==0) ? g0v : (wave==1) ? g1v : (wave==2) ? g2v : g3v;

  // prologue: issue W1[cc=0] -> buf0 (8 gld16/wave = 32 KB total)
  #pragma unroll
  for (int i = 0; i < 8; ++i) {
    int gidx = wave*512 + i*64;
    gld16(w1lo + (size_t)(gidx + lane)*8, &Wbuf[0][(size_t)gidx*8]);
  }

  // X -> areg direct (this wave's sample, 16 rows x K=512, fp32->bf16): 64 VGPR
  short8 areg[16];
  {
    const float* xb = X + (size_t)(smpw*P_N + rA)*D_N + cA;
    #pragma unroll
    for (int ks = 0; ks < 16; ++ks) {
      float4 f0 = *(const float4*)(xb + ks*32);
      float4 f1 = *(const float4*)(xb + ks*32 + 4);
      short8 v;
      v[0]=bfq(f0.x); v[1]=bfq(f0.y); v[2]=bfq(f0.z); v[3]=bfq(f0.w);
      v[4]=bfq(f1.x); v[5]=bfq(f1.y); v[6]=bfq(f1.z); v[7]=bfq(f1.w);
      areg[ks] = v;
    }
  }

  const int mp = wave & 1;             // GEMM2 sample pair {mp, mp+2}
  const int dh = wave >> 1;            // GEMM2 d-half [dh*256, +256)

  floatx4 Yacc[2][16];
  #pragma unroll
  for (int a = 0; a < 2; ++a)
    #pragma unroll
    for (int q = 0; q < 16; ++q) Yacc[a][q] = (floatx4){0.f,0.f,0.f,0.f};

  for (int cc = 0; cc < 2*NCH; ++cc) {
    const int xp = cc >> 6;
    const int fc = cc & 63;

    // b1 prefetch for THIS iter: issued before W2 batch so vmcnt(8) drains it for free
    const float* b1p = b1 + (xp ? e_hi : e_lo)*F_N + fc*FC + rA;
    float b1v0 = b1p[0];
    float b1v1 = b1p[16];

    { // stage W2[cc] -> buf1 (prev GEMM2 finished reading buf1 before last barrier)
      const u16* gsrc = (xp ? w2hi : w2lo) + (size_t)fc*FC*D_N;
      #pragma unroll
      for (int i = 0; i < 8; ++i) {
        int gidx = wave*512 + i*64;
        gld16(gsrc + (size_t)(gidx + lane)*8, &Wbuf[1][(size_t)gidx*8]);
      }
    }
    asm volatile("s_waitcnt vmcnt(8)" ::: "memory");   // W1[cc]+b1 landed (W2 in flight)
    bar_lgkm();                                        // all waves' W1 visible

    // GEMM1: h[16x32] per wave over K=512; A in regs, B lane-linear (conflict-free)
    floatx4 acc1[2];
    acc1[0] = (floatx4){0.f,0.f,0.f,0.f};
    acc1[1] = (floatx4){0.f,0.f,0.f,0.f};
    __builtin_amdgcn_s_setprio(1);
    #pragma unroll
    for (int ks = 0; ks < 16; ++ks) {
      short8 bb0 = *(const short8*)&Wbuf[0][((      ks)*64 + lane)*8];
      short8 bb1 = *(const short8*)&Wbuf[0][((16  + ks)*64 + lane)*8];
      acc1[0] = __builtin_amdgcn_mfma_f32_16x16x32_bf16(areg[ks], bb0, acc1[0], 0, 0, 0);
      acc1[1] = __builtin_amdgcn_mfma_f32_16x16x32_bf16(areg[ks], bb1, acc1[1], 0, 0, 0);
    }
    __builtin_amdgcn_s_setprio(0);
    { // bias + gate + GELU via sigmoid identity: 0.5*(1+tanh(u)) = sigmoid(2u)
      float gate = xp ? gw.y : gw.x;
      #pragma unroll
      for (int nt = 0; nt < 2; ++nt) {
        float b1v = nt ? b1v1 : b1v0;
        int wbase = wave*512 + (nt*2 + (rA >> 3))*128 + (rA & 7) + (lane >> 4)*32;
        #pragma unroll
        for (int i = 0; i < 4; ++i) {
          float v = acc1[nt][i] + b1v;
          float u2 = 1.5957691216057308f * (v + 0.044715f*v*v*v);  // 2*sqrt(2/pi)*(...)
          float sg = 1.f / (1.f + __expf(-u2));
          hfl[wbase + i*8] = (u16)bfq(v * sg * gate);
        }
      }
    }
    bar_lgkm();                                        // h visible; buf0 reads done

    { // stage W1[cc+1] -> buf0 (lands under GEMM2; dummy re-stage on last iter keeps count)
      int nc = (cc + 1 < 2*NCH) ? cc + 1 : cc;
      const u16* wn = ((nc >> 6) ? w1hi : w1lo) + (size_t)(nc & 63)*FC*D_N;
      #pragma unroll
      for (int i = 0; i < 8; ++i) {
        int gidx = wave*512 + i*64;
        gld16(wn + (size_t)(gidx + lane)*8, &Wbuf[0][(size_t)gidx*8]);
      }
    }
    asm volatile("s_waitcnt vmcnt(8)" ::: "memory");   // W2[cc] landed (W1[cc+1] in flight)
    bar_lgkm();

    // GEMM2: Y[2 samples x 256 d] += h @ W2chunk; A-frags conflict-free, B lane-linear
    short8 a0 = *(const short8*)&hfl[(size_t)mp*512 + lane*8];
    short8 a1 = *(const short8*)&hfl[(size_t)(mp + 2)*512 + lane*8];
    __builtin_amdgcn_s_setprio(1);
    #pragma unroll
    for (int n2 = 0; n2 < 16; ++n2) {
      short8 bb = *(const short8*)&Wbuf[1][((dh*16 + n2)*64 + lane)*8];
      Yacc[0][n2] = __builtin_amdgcn_mfma_f32_16x16x32_bf16(a0, bb, Yacc[0][n2], 0, 0, 0);
      Yacc[1][n2] = __builtin_amdgcn_mfma_f32_16x16x32_bf16(a1, bb, Yacc[1][n2], 0, 0, 0);
    }
    __builtin_amdgcn_s_setprio(0);
    bar_lgkm();                                        // buf1 + hfl reads done
  }
  asm volatile("s_waitcnt vmcnt(0)" ::: "memory");     // drain dummy stage before exit

  // epilogue: out[b,p,d] = Y + gate-weighted b2 (C-layout: col=lane&15, row=quad*4+i)
  #pragma unroll
  for (int a = 0; a < 2; ++a) {
    int si = mp + a*2;
    if (si >= nsamp) continue;
    int smp = (si==0) ? s0v : (si==1) ? s1v : (si==2) ? s2v : s3v;
    float2 gv = (si==0) ? g0v : (si==1) ? g1v : (si==2) ? g2v : g3v;
    #pragma unroll
    for (int n2 = 0; n2 < 16; ++n2) {
      int dcol = dh*256 + n2*16 + rA;
      float b2v = gv.x * b2[e_lo*D_N + dcol]
                + gv.y * b2[e_hi*D_N + dcol];
      #pragma unroll
      for (int i = 0; i < 4; ++i) {
        int p = (lane >> 4)*4 + i;
        out[(size_t)(smp*P_N + p)*D_N + dcol] = Yacc[a][n2][i] + b2v;
      }
    }
  }
}

extern "C" void kernel_launch(void* const* d_in, const int* in_sizes, int n_in,
                              void* d_out, int out_size, void* d_ws, size_t ws_size,
                              hipStream_t stream) {
  const float* X   = (const float*)d_in[0];
  // d_in[1] patch_embedding: only defines output shape; values unused
  const float* aff = (const float*)d_in[2];
  const float* noi = (const float*)d_in[3];
  const float* W1  = (const float*)d_in[4];
  const float* b1  = (const float*)d_in[5];
  const float* W2  = (const float*)d_in[6];
  const float* b2  = (const float*)d_in[7];

  char* ws   = (char*)d_ws;
  int* cnt   = (int*)(ws + CNT_OFF);
  int* pref  = (int*)(ws + PREF_OFF);
  int* slist = (int*)(ws + SL_OFF);
  float2* glist = (float2*)(ws + GL_OFF);
  u16* W1f   = (u16*)(ws + W1F_OFF);
  u16* W2f   = (u16*)(ws + W2F_OFF);

  hipMemsetAsync(cnt, 0, NPID*sizeof(int), stream);
  hipLaunchKernelGGL(router_kernel, dim3(B_N/256), dim3(256), 0, stream, aff, noi, cnt, slist, glist);
  hipLaunchKernelGGL(plan_kernel, dim3(1), dim3(64), 0, stream, cnt, pref);
  hipLaunchKernelGGL(prep_w1, dim3(4096), dim3(256), 0, stream, W1, (u16*)W1f);
  hipLaunchKernelGGL(prep_w2, dim3(4096), dim3(256), 0, stream, W2, (u16*)W2f);
  hipLaunchKernelGGL(moe_main, dim3(GRID), dim3(256), 0, stream,
                     X, W1f, W2f, b1, b2, cnt, pref, slist, glist, (float*)d_out);
}